// Round 6
// baseline (543.537 us; speedup 1.0000x reference)
//
#include <hip/hip_runtime.h>

#define T_    128
#define B_    64
#define H_    2048
#define L_    4
#define C_    10
#define BN_EPS 1e-5f
#define K0REAL 144
#define K0PAD  160

typedef __attribute__((ext_vector_type(8))) short bf16x8;
typedef __attribute__((ext_vector_type(4))) float f32x4;

__device__ __forceinline__ short f2bf(float f) {
    union { float f; unsigned u; } v; v.f = f;
    unsigned r = (v.u + 0x7FFFu + ((v.u >> 16) & 1u)) >> 16;
    return (short)r;
}
__device__ __forceinline__ float bf2f(short s) {
    union { unsigned u; float f; } v; v.u = ((unsigned)(unsigned short)s) << 16;
    return v.f;
}
__device__ __forceinline__ void gload16(const short* g, short* l) {
    __builtin_amdgcn_global_load_lds(
        (const __attribute__((address_space(1))) void*)g,
        (__attribute__((address_space(3))) void*)l, 16, 0, 0);
}

#define SBAR() do { __builtin_amdgcn_sched_barrier(0); \
                    __builtin_amdgcn_s_barrier();      \
                    __builtin_amdgcn_sched_barrier(0); } while (0)

// ---------------------------------------------------------------------------
// 256x256 / BK=64 / 8-wave GEMM, 4 phases per K-tile, ONE barrier per phase.
// Zb[M,N](bf16) = A[M,Kb](bf16) @ Bw[N,Kb](bf16)^T + bias
// Phase = {ds_reads ; stage ; setprio MFMA ; SBAR}: reads of phase p are
// consumed by p's MFMA before p's barrier, so staging region R in the phase
// after R's last-read phase is race-free. Counted vmcnt(8) once per K-tile.
// Grid must be (M/256, 8); Kb % 64 == 0, Kb/64 >= 2.
// ---------------------------------------------------------------------------
__global__ __launch_bounds__(512, 2) void gemm_bf16_8ph(
    const short* __restrict__ A, const short* __restrict__ Bw,
    const float* __restrict__ bias, short* __restrict__ Zb,
    int M, int N, int Kb)
{
    __shared__ short As[2][256 * 64];
    __shared__ short Bs[2][256 * 64];

    const int tid  = threadIdx.x;
    const int wid  = tid >> 6;
    const int lane = tid & 63;

    // n-panel == XCD id (linear block id % 8 round-robins XCDs)
    const int lin = blockIdx.y * gridDim.x + blockIdx.x;
    const int m0  = (lin >> 3) * 256;
    const int n0  = (lin & 7) * 256;

    const int wm  = (wid >> 2) * 128;
    const int wn  = (wid & 3) * 64;

    const int fr  = lane & 15;
    const int fq  = lane >> 4;
    const int fr7 = fr & 7;

    const int s_sub   = wid * 2;
    const int s_rowi  = lane >> 3;
    const int s_chunk = (lane & 7) ^ s_rowi;   // pre-swizzled global col chunk

    auto stA = [&](int kt, int h, int i) {
        const int r = h * 128 + (s_sub + i) * 8 + s_rowi;
        gload16(A + (size_t)(m0 + r) * Kb + kt * 64 + s_chunk * 8,
                &As[kt & 1][h * 8192 + (s_sub + i) * 512 + lane * 8]);
    };
    auto stB = [&](int kt, int h, int i) {
        const int r = h * 128 + (s_sub + i) * 8 + s_rowi;
        gload16(Bw + (size_t)(n0 + r) * Kb + kt * 64 + s_chunk * 8,
                &Bs[kt & 1][h * 8192 + (s_sub + i) * 512 + lane * 8]);
    };
    auto rdA = [&](int buf, int m, int kk) -> bf16x8 {
        const int ar = wm + m * 16 + fr;
        const int slot = (kk * 4 + fq) ^ fr7;
        return *(const bf16x8*)&As[buf][ar * 64 + slot * 8];
    };
    auto rdB = [&](int buf, int n, int kk) -> bf16x8 {
        const int br = wn + n * 16 + fr;
        const int slot = (kk * 4 + fq) ^ fr7;
        return *(const bf16x8*)&Bs[buf][br * 64 + slot * 8];
    };

    f32x4 acc[8][4];
#pragma unroll
    for (int m = 0; m < 8; ++m)
#pragma unroll
        for (int n = 0; n < 4; ++n)
            acc[m][n] = (f32x4){0.f, 0.f, 0.f, 0.f};

    const int NK = Kb >> 6;

    // prologue: stage tiles 0,1 (16 loads); wait tile 0 (8 may remain)
    stA(0, 0, 0); stA(0, 0, 1); stA(0, 1, 0); stA(0, 1, 1);
    stB(0, 0, 0); stB(0, 0, 1); stB(0, 1, 0); stB(0, 1, 1);
    stA(1, 0, 0); stA(1, 0, 1); stA(1, 1, 0); stA(1, 1, 1);
    stB(1, 0, 0); stB(1, 0, 1); stB(1, 1, 0); stB(1, 1, 1);
    asm volatile("s_waitcnt vmcnt(8)" ::: "memory");
    SBAR();

    bf16x8 aF[4][2], b0[2][2], b1[2][2];

#pragma unroll 1
    for (int g = 0; g < NK; ++g) {
        const int buf = g & 1;
        // ---- P1: rd A m0-3 + B n0-1; MFMA (m0-3, n0-1) -------------------
#pragma unroll
        for (int m = 0; m < 4; ++m)
#pragma unroll
            for (int kk = 0; kk < 2; ++kk) aF[m][kk] = rdA(buf, m, kk);
#pragma unroll
        for (int n = 0; n < 2; ++n)
#pragma unroll
            for (int kk = 0; kk < 2; ++kk) b0[n][kk] = rdB(buf, n, kk);
        __builtin_amdgcn_s_setprio(1);
#pragma unroll
        for (int m = 0; m < 4; ++m)
#pragma unroll
            for (int n = 0; n < 2; ++n)
#pragma unroll
                for (int kk = 0; kk < 2; ++kk)
                    acc[m][n] = __builtin_amdgcn_mfma_f32_16x16x32_bf16(
                        aF[m][kk], b0[n][kk], acc[m][n], 0, 0, 0);
        __builtin_amdgcn_s_setprio(0);
        SBAR();
        // ---- P2: rd B n2-3; MFMA (m0-3, n2-3) ----------------------------
#pragma unroll
        for (int n = 0; n < 2; ++n)
#pragma unroll
            for (int kk = 0; kk < 2; ++kk) b1[n][kk] = rdB(buf, n + 2, kk);
        __builtin_amdgcn_s_setprio(1);
#pragma unroll
        for (int m = 0; m < 4; ++m)
#pragma unroll
            for (int n = 0; n < 2; ++n)
#pragma unroll
                for (int kk = 0; kk < 2; ++kk)
                    acc[m][n + 2] = __builtin_amdgcn_mfma_f32_16x16x32_bf16(
                        aF[m][kk], b1[n][kk], acc[m][n + 2], 0, 0, 0);
        __builtin_amdgcn_s_setprio(0);
        SBAR();
        // ---- P3: rd A m4-7; stage B(g+2) [B(g) fully read by end-P2 bar];
        //          MFMA (m4-7, n2-3) ---------------------------------------
#pragma unroll
        for (int m = 0; m < 4; ++m)
#pragma unroll
            for (int kk = 0; kk < 2; ++kk) aF[m][kk] = rdA(buf, m + 4, kk);
        if (g + 2 < NK) { stB(g + 2, 0, 0); stB(g + 2, 0, 1);
                          stB(g + 2, 1, 0); stB(g + 2, 1, 1); }
        __builtin_amdgcn_s_setprio(1);
#pragma unroll
        for (int m = 0; m < 4; ++m)
#pragma unroll
            for (int n = 0; n < 2; ++n)
#pragma unroll
                for (int kk = 0; kk < 2; ++kk)
                    acc[m + 4][n + 2] = __builtin_amdgcn_mfma_f32_16x16x32_bf16(
                        aF[m][kk], b1[n][kk], acc[m + 4][n + 2], 0, 0, 0);
        __builtin_amdgcn_s_setprio(0);
        SBAR();
        // ---- P4: stage A(g+2) [A(g) fully read by end-P3 bar];
        //          MFMA (m4-7, n0-1); counted vmcnt ------------------------
        if (g + 2 < NK) { stA(g + 2, 0, 0); stA(g + 2, 0, 1);
                          stA(g + 2, 1, 0); stA(g + 2, 1, 1); }
        __builtin_amdgcn_s_setprio(1);
#pragma unroll
        for (int m = 0; m < 4; ++m)
#pragma unroll
            for (int n = 0; n < 2; ++n)
#pragma unroll
                for (int kk = 0; kk < 2; ++kk)
                    acc[m + 4][n] = __builtin_amdgcn_mfma_f32_16x16x32_bf16(
                        aF[m][kk], b0[n][kk], acc[m + 4][n], 0, 0, 0);
        __builtin_amdgcn_s_setprio(0);
        if (g + 2 < NK) asm volatile("s_waitcnt vmcnt(8)" ::: "memory");
        else            asm volatile("s_waitcnt vmcnt(0)" ::: "memory");
        SBAR();
    }

    // epilogue: D map col=lane&15, row=(lane>>4)*4+r; bf16 out
#pragma unroll
    for (int m = 0; m < 8; ++m) {
#pragma unroll
        for (int n = 0; n < 4; ++n) {
            const int col = n0 + wn + n * 16 + fr;
            const float bsum = bias[col];
#pragma unroll
            for (int r = 0; r < 4; ++r) {
                const int row = m0 + wm + m * 16 + fq * 4 + r;
                Zb[(size_t)row * N + col] = f2bf(acc[m][n][r] + bsum);
            }
        }
    }
}

// ---------------------------------------------------------------------------
// 128x128 / BK=32 GEMM — layer-0 (K=160) only; bf16 output.
// ---------------------------------------------------------------------------
__global__ __launch_bounds__(256) void gemm_bf16_lds(
    const short* __restrict__ A, const short* __restrict__ Bw,
    const float* __restrict__ bias,
    short* __restrict__ Zb, int M, int N, int Kb)
{
    __shared__ short As[128 * 32];
    __shared__ short Bs[128 * 32];

    const int tid = threadIdx.x;
    const int nwg = gridDim.x * gridDim.y;
    int lin = blockIdx.y * gridDim.x + blockIdx.x;
    lin = (lin & 7) * (nwg >> 3) + (lin >> 3);
    const int bx = lin % gridDim.x;
    const int by = lin / gridDim.x;
    const int m0 = by * 128;
    const int n0 = bx * 128;

    const int srow = tid >> 2;
    const int scol = (tid & 3) * 8;

    const int wid  = tid >> 6;
    const int lane = tid & 63;
    const int wm   = (wid >> 1) * 64;
    const int wn   = (wid & 1) * 64;
    const int fr   = lane & 15;
    const int fk   = (lane >> 4) * 8;

    f32x4 acc[4][4];
#pragma unroll
    for (int m = 0; m < 4; ++m)
#pragma unroll
        for (int n = 0; n < 4; ++n)
            acc[m][n] = (f32x4){0.f, 0.f, 0.f, 0.f};

    const short* Abase = A + (size_t)m0 * Kb;
    const short* Bbase = Bw + (size_t)n0 * Kb;

    for (int k0 = 0; k0 < Kb; k0 += 32) {
        gload16(Abase + (size_t)srow        * Kb + k0 + scol, &As[tid * 8]);
        gload16(Abase + (size_t)(srow + 64) * Kb + k0 + scol, &As[2048 + tid * 8]);
        gload16(Bbase + (size_t)srow        * Kb + k0 + scol, &Bs[tid * 8]);
        gload16(Bbase + (size_t)(srow + 64) * Kb + k0 + scol, &Bs[2048 + tid * 8]);
        __syncthreads();

        bf16x8 af[4], bfv[4];
#pragma unroll
        for (int m = 0; m < 4; ++m)
            af[m] = *(const bf16x8*)&As[(wm + m * 16 + fr) * 32 + fk];
#pragma unroll
        for (int n = 0; n < 4; ++n)
            bfv[n] = *(const bf16x8*)&Bs[(wn + n * 16 + fr) * 32 + fk];

#pragma unroll
        for (int m = 0; m < 4; ++m)
#pragma unroll
            for (int n = 0; n < 4; ++n)
                acc[m][n] = __builtin_amdgcn_mfma_f32_16x16x32_bf16(
                    af[m], bfv[n], acc[m][n], 0, 0, 0);
        __syncthreads();
    }

    const int orow = (lane >> 4) * 4;
#pragma unroll
    for (int m = 0; m < 4; ++m) {
#pragma unroll
        for (int n = 0; n < 4; ++n) {
            const int col = n0 + wn + n * 16 + fr;
            const float bsum = bias[col];
#pragma unroll
            for (int r = 0; r < 4; ++r) {
                const int row = m0 + wm + m * 16 + orow + r;
                Zb[(size_t)row * N + col] = f2bf(acc[m][n][r] + bsum);
            }
        }
    }
}

// ---------------------------------------------------------------------------
// IndRNN scan: bf16 z in, fp32 recurrence, bf16 h out + BN stats.
// 4 channels/thread (short4), 2-deep t-prefetch. store_all==0: only t=T-1.
// ---------------------------------------------------------------------------
__global__ __launch_bounds__(256) void scan_bf16_v2(
    const short* __restrict__ Zb, const float* __restrict__ u,
    short* __restrict__ Hb, float* __restrict__ sum, float* __restrict__ sumsq,
    int store_all)
{
    const int tid  = blockIdx.x * blockDim.x + threadIdx.x;   // 0..32767
    const int idx4 = tid * 4;
    const int h4   = idx4 & (H_ - 1);
    const float4 uu = *(const float4*)(u + h4);
    const float uv[4] = {uu.x, uu.y, uu.z, uu.w};
    float hp[4] = {0.f, 0.f, 0.f, 0.f};
    float s1[4] = {0.f, 0.f, 0.f, 0.f};
    float s2[4] = {0.f, 0.f, 0.f, 0.f};

    short4 z0 = *(const short4*)(Zb + idx4);
    short4 z1 = *(const short4*)(Zb + (size_t)(B_ * H_) + idx4);

    for (int t = 0; t < T_; ++t) {
        short4 zc = z0;
        z0 = z1;
        if (t + 2 < T_) z1 = *(const short4*)(Zb + (size_t)(t + 2) * (B_ * H_) + idx4);
        const float zf[4] = {bf2f(zc.x), bf2f(zc.y), bf2f(zc.z), bf2f(zc.w)};
        short hs[4];
#pragma unroll
        for (int j = 0; j < 4; ++j) {
            float hv = fmaxf(zf[j] + uv[j] * hp[j], 0.f);
            hp[j] = hv;
            s1[j] += hv;
            s2[j] += hv * hv;
            hs[j] = f2bf(hv);
        }
        if (store_all || t == T_ - 1) {
            short4 o = {hs[0], hs[1], hs[2], hs[3]};
            *(short4*)(Hb + (size_t)t * (B_ * H_) + idx4) = o;
        }
    }
#pragma unroll
    for (int j = 0; j < 4; ++j) {
        atomicAdd(&sum[h4 + j], s1[j]);
        atomicAdd(&sumsq[h4 + j], s2[j]);
    }
}

// ---------------------------------------------------------------------------
__global__ void bn_finalize(
    const float* __restrict__ sum, const float* __restrict__ sumsq,
    const float* __restrict__ gamma, const float* __restrict__ beta,
    float* __restrict__ scale, float* __restrict__ shift)
{
    const int h = blockIdx.x * blockDim.x + threadIdx.x;
    if (h >= H_) return;
    const float inv_n = 1.f / (float)(T_ * B_);
    const float m = sum[h] * inv_n;
    const float v = sumsq[h] * inv_n - m * m;
    const float s = gamma[h] * rsqrtf(v + BN_EPS);
    scale[h] = s;
    shift[h] = beta[h] - m * s;
}

// ---------------------------------------------------------------------------
// Fused BN fold: Wb[n,k] = bf16(W[n,k]*scale[k]);
//                bias2[n] = b[n] + sum_k shift[k]*W[n,k].  One wave per row.
// ---------------------------------------------------------------------------
__global__ __launch_bounds__(256) void fold_wb(
    const float* __restrict__ Wf, const float* __restrict__ scale,
    const float* __restrict__ shift, const float* __restrict__ b,
    short* __restrict__ Wb, float* __restrict__ bias2)
{
    const int wrow = (blockIdx.x * blockDim.x + threadIdx.x) >> 6;
    const int lane = threadIdx.x & 63;
    if (wrow >= H_) return;
    const float* wr = Wf + (size_t)wrow * H_;
    short* wb = Wb + (size_t)wrow * H_;
    float acc = 0.f;
    for (int k4 = lane * 4; k4 < H_; k4 += 256) {
        float4 w  = *(const float4*)(wr + k4);
        float4 sc = *(const float4*)(scale + k4);
        float4 sh = *(const float4*)(shift + k4);
        short4 s;
        s.x = f2bf(w.x * sc.x); s.y = f2bf(w.y * sc.y);
        s.z = f2bf(w.z * sc.z); s.w = f2bf(w.w * sc.w);
        *(short4*)(wb + k4) = s;
        acc += w.x * sh.x + w.y * sh.y + w.z * sh.z + w.w * sh.w;
    }
#pragma unroll
    for (int o = 32; o > 0; o >>= 1) acc += __shfl_down(acc, o);
    if (lane == 0) bias2[wrow] = acc + b[wrow];
}

// ---------------------------------------------------------------------------
// fp32 [rows][K0REAL] -> bf16 [rows][K0PAD] zero-padded
// ---------------------------------------------------------------------------
__global__ __launch_bounds__(256) void conv_pad(
    const float* __restrict__ X, short* __restrict__ Xb, int rows)
{
    const int npr = K0PAD / 4;   // 40
    const int idx = blockIdx.x * blockDim.x + threadIdx.x;
    if (idx >= rows * npr) return;
    const int r = idx / npr;
    const int c4 = (idx - r * npr) * 4;
    short4 s = {0, 0, 0, 0};
    if (c4 < K0REAL) {
        float4 v = *(const float4*)(X + (size_t)r * K0REAL + c4);
        s.x = f2bf(v.x); s.y = f2bf(v.y); s.z = f2bf(v.z); s.w = f2bf(v.w);
    }
    *(short4*)(Xb + (size_t)r * K0PAD + c4) = s;
}

// ---------------------------------------------------------------------------
// out[b,c] = sum_h (bf2f(Hb[b,h])*scale[h]+shift[h]) * Wlast[c,h] + blast[c]
// ---------------------------------------------------------------------------
__global__ __launch_bounds__(256) void final_proj(
    const short* __restrict__ Hb, const float* __restrict__ scale,
    const float* __restrict__ shift, const float* __restrict__ Wlast,
    const float* __restrict__ blast, float* __restrict__ out)
{
    const int wave = (blockIdx.x * blockDim.x + threadIdx.x) >> 6;
    const int lane = threadIdx.x & 63;
    if (wave >= B_ * C_) return;
    const int b = wave / C_;
    const int c = wave % C_;
    float acc = 0.f;
    for (int h = lane; h < H_; h += 64) {
        float hv = bf2f(Hb[(size_t)b * H_ + h]) * scale[h] + shift[h];
        acc += hv * Wlast[(size_t)c * H_ + h];
    }
#pragma unroll
    for (int o = 32; o > 0; o >>= 1) acc += __shfl_down(acc, o);
    if (lane == 0) out[(size_t)b * C_ + c] = acc + blast[c];
}

// ---------------------------------------------------------------------------
extern "C" void kernel_launch(void* const* d_in, const int* in_sizes, int n_in,
                              void* d_out, int out_size, void* d_ws, size_t ws_size,
                              hipStream_t stream)
{
    const float* x      = (const float*)d_in[0];  // [8192,144]
    const float* W0     = (const float*)d_in[1];  // [2048,144]
    const float* Ws     = (const float*)d_in[2];  // [3,2048,2048]
    const float* bs     = (const float*)d_in[3];  // [4,2048]
    const float* us     = (const float*)d_in[4];
    const float* gammas = (const float*)d_in[5];
    const float* betas  = (const float*)d_in[6];
    const float* Wlast  = (const float*)d_in[7];  // [10,2048]
    const float* blast  = (const float*)d_in[8];
    float* out = (float*)d_out;

    char* ws = (char*)d_ws;
    short* zb      = (short*)ws;                            // 32 MB bf16 z
    short* Ab      = (short*)(ws + (size_t)32 * 1048576);   // 32 MB bf16 h
    short* Wb      = (short*)(ws + (size_t)64 * 1048576);   // 8 MB folded W
    short* X0b     = (short*)(ws + (size_t)72 * 1048576);   // 2.62 MB
    short* W0b     = (short*)(ws + (size_t)75 * 1048576);   // 0.66 MB
    float* sum     = (float*)(ws + (size_t)76 * 1048576);
    float* sumsq   = sum + H_;
    float* bnscale = sumsq + H_;
    float* bnshift = bnscale + H_;
    float* bias2   = bnshift + H_;

    const int M = T_ * B_;   // 8192

    conv_pad<<<(M * (K0PAD / 4) + 255) / 256, 256, 0, stream>>>(x, X0b, M);
    conv_pad<<<(H_ * (K0PAD / 4) + 255) / 256, 256, 0, stream>>>(W0, W0b, H_);

    // layer 0 projection (K padded to 160)
    gemm_bf16_lds<<<dim3(H_ / 128, M / 128), 256, 0, stream>>>(
        X0b, W0b, bs, zb, M, H_, K0PAD);

    const dim3 g256(M / 256, H_ / 256);   // (32, 8) = 256 blocks
    for (int l = 0; l < L_; ++l) {
        hipMemsetAsync(sum, 0, 2 * H_ * sizeof(float), stream);
        scan_bf16_v2<<<(B_ * H_ / 4) / 256, 256, 0, stream>>>(
            zb, us + l * H_, Ab, sum, sumsq, (l < L_ - 1) ? 1 : 0);
        bn_finalize<<<H_ / 256, 256, 0, stream>>>(sum, sumsq,
                                                  gammas + l * H_, betas + l * H_,
                                                  bnscale, bnshift);
        if (l < L_ - 1) {
            const float* Wl = Ws + (size_t)l * H_ * H_;
            fold_wb<<<(H_ * 64) / 256, 256, 0, stream>>>(Wl, bnscale, bnshift,
                                                         bs + (l + 1) * H_, Wb, bias2);
            gemm_bf16_8ph<<<g256, 512, 0, stream>>>(Ab, Wb, bias2, zb, M, H_, H_);
        }
    }

    final_proj<<<(B_ * C_ * 64 + 255) / 256, 256, 0, stream>>>(
        Ab + (size_t)(T_ - 1) * B_ * H_, bnscale, bnshift, Wlast, blast, out);
}

// Round 7
// 503.740 us; speedup vs baseline: 1.0790x; 1.0790x over previous
//
#include <hip/hip_runtime.h>

#define T_    128
#define B_    64
#define H_    2048
#define L_    4
#define C_    10
#define BN_EPS 1e-5f
#define K0REAL 144
#define K0PAD  160

typedef __attribute__((ext_vector_type(8))) short bf16x8;
typedef __attribute__((ext_vector_type(4))) float f32x4;

__device__ __forceinline__ short f2bf(float f) {
    union { float f; unsigned u; } v; v.f = f;
    unsigned r = (v.u + 0x7FFFu + ((v.u >> 16) & 1u)) >> 16;
    return (short)r;
}
__device__ __forceinline__ float bf2f(short s) {
    union { unsigned u; float f; } v; v.u = ((unsigned)(unsigned short)s) << 16;
    return v.f;
}
__device__ __forceinline__ void gload16(const short* g, short* l) {
    __builtin_amdgcn_global_load_lds(
        (const __attribute__((address_space(1))) void*)g,
        (__attribute__((address_space(3))) void*)l, 16, 0, 0);
}

#define SBAR() do { __builtin_amdgcn_sched_barrier(0); \
                    __builtin_amdgcn_s_barrier();      \
                    __builtin_amdgcn_sched_barrier(0); } while (0)

// ---------------------------------------------------------------------------
// 256x256 / BK=64 / 8-wave GEMM, 4 phases per K-tile, ONE barrier per phase.
// Zb[M,N](bf16) = A[M,Kb](bf16) @ Bw[N,Kb](bf16)^T + bias
// XCD-chunked block map: XCD j (lin&7) owns m-panels 4j..4j+3 x all 8
// n-panels -> per-XCD L2 footprint A 4MB + B 8MB (vs 33MB for n-pinned).
// Counted vmcnt(8) once per K-tile. Grid must be (M/256, 8) = 256 blocks.
// ---------------------------------------------------------------------------
__global__ __launch_bounds__(512, 2) void gemm_bf16_8ph(
    const short* __restrict__ A, const short* __restrict__ Bw,
    const float* __restrict__ bias, short* __restrict__ Zb,
    int M, int N, int Kb)
{
    __shared__ short As[2][256 * 64];
    __shared__ short Bs[2][256 * 64];

    const int tid  = threadIdx.x;
    const int wid  = tid >> 6;
    const int lane = tid & 63;

    // bijective XCD 4x8-chunk map (256 blocks, 1/CU, all co-resident)
    const int lin = blockIdx.y * gridDim.x + blockIdx.x;
    const int xcd = lin & 7;
    const int loc = lin >> 3;
    const int m0  = (xcd * 4 + (loc & 3)) * 256;
    const int n0  = (loc >> 2) * 256;

    const int wm  = (wid >> 2) * 128;
    const int wn  = (wid & 3) * 64;

    const int fr  = lane & 15;
    const int fq  = lane >> 4;
    const int fr7 = fr & 7;

    const int s_sub   = wid * 2;
    const int s_rowi  = lane >> 3;
    const int s_chunk = (lane & 7) ^ s_rowi;   // pre-swizzled global col chunk

    auto stA = [&](int kt, int h, int i) {
        const int r = h * 128 + (s_sub + i) * 8 + s_rowi;
        gload16(A + (size_t)(m0 + r) * Kb + kt * 64 + s_chunk * 8,
                &As[kt & 1][h * 8192 + (s_sub + i) * 512 + lane * 8]);
    };
    auto stB = [&](int kt, int h, int i) {
        const int r = h * 128 + (s_sub + i) * 8 + s_rowi;
        gload16(Bw + (size_t)(n0 + r) * Kb + kt * 64 + s_chunk * 8,
                &Bs[kt & 1][h * 8192 + (s_sub + i) * 512 + lane * 8]);
    };
    auto rdA = [&](int buf, int m, int kk) -> bf16x8 {
        const int ar = wm + m * 16 + fr;
        const int slot = (kk * 4 + fq) ^ fr7;
        return *(const bf16x8*)&As[buf][ar * 64 + slot * 8];
    };
    auto rdB = [&](int buf, int n, int kk) -> bf16x8 {
        const int br = wn + n * 16 + fr;
        const int slot = (kk * 4 + fq) ^ fr7;
        return *(const bf16x8*)&Bs[buf][br * 64 + slot * 8];
    };

    f32x4 acc[8][4];
#pragma unroll
    for (int m = 0; m < 8; ++m)
#pragma unroll
        for (int n = 0; n < 4; ++n)
            acc[m][n] = (f32x4){0.f, 0.f, 0.f, 0.f};

    const int NK = Kb >> 6;

    // prologue: stage tiles 0,1 (16 loads); wait tile 0 (8 may remain)
    stA(0, 0, 0); stA(0, 0, 1); stA(0, 1, 0); stA(0, 1, 1);
    stB(0, 0, 0); stB(0, 0, 1); stB(0, 1, 0); stB(0, 1, 1);
    stA(1, 0, 0); stA(1, 0, 1); stA(1, 1, 0); stA(1, 1, 1);
    stB(1, 0, 0); stB(1, 0, 1); stB(1, 1, 0); stB(1, 1, 1);
    asm volatile("s_waitcnt vmcnt(8)" ::: "memory");
    SBAR();

    bf16x8 aF[4][2], b0[2][2], b1[2][2];

#pragma unroll 1
    for (int g = 0; g < NK; ++g) {
        const int buf = g & 1;
        // ---- P1: rd A m0-3 + B n0-1; MFMA (m0-3, n0-1) -------------------
#pragma unroll
        for (int m = 0; m < 4; ++m)
#pragma unroll
            for (int kk = 0; kk < 2; ++kk) aF[m][kk] = rdA(buf, m, kk);
#pragma unroll
        for (int n = 0; n < 2; ++n)
#pragma unroll
            for (int kk = 0; kk < 2; ++kk) b0[n][kk] = rdB(buf, n, kk);
        __builtin_amdgcn_s_setprio(1);
#pragma unroll
        for (int m = 0; m < 4; ++m)
#pragma unroll
            for (int n = 0; n < 2; ++n)
#pragma unroll
                for (int kk = 0; kk < 2; ++kk)
                    acc[m][n] = __builtin_amdgcn_mfma_f32_16x16x32_bf16(
                        aF[m][kk], b0[n][kk], acc[m][n], 0, 0, 0);
        __builtin_amdgcn_s_setprio(0);
        SBAR();
        // ---- P2: rd B n2-3; MFMA (m0-3, n2-3) ----------------------------
#pragma unroll
        for (int n = 0; n < 2; ++n)
#pragma unroll
            for (int kk = 0; kk < 2; ++kk) b1[n][kk] = rdB(buf, n + 2, kk);
        __builtin_amdgcn_s_setprio(1);
#pragma unroll
        for (int m = 0; m < 4; ++m)
#pragma unroll
            for (int n = 0; n < 2; ++n)
#pragma unroll
                for (int kk = 0; kk < 2; ++kk)
                    acc[m][n + 2] = __builtin_amdgcn_mfma_f32_16x16x32_bf16(
                        aF[m][kk], b1[n][kk], acc[m][n + 2], 0, 0, 0);
        __builtin_amdgcn_s_setprio(0);
        SBAR();
        // ---- P3: rd A m4-7; stage B(g+2); MFMA (m4-7, n2-3) --------------
#pragma unroll
        for (int m = 0; m < 4; ++m)
#pragma unroll
            for (int kk = 0; kk < 2; ++kk) aF[m][kk] = rdA(buf, m + 4, kk);
        if (g + 2 < NK) { stB(g + 2, 0, 0); stB(g + 2, 0, 1);
                          stB(g + 2, 1, 0); stB(g + 2, 1, 1); }
        __builtin_amdgcn_s_setprio(1);
#pragma unroll
        for (int m = 0; m < 4; ++m)
#pragma unroll
            for (int n = 0; n < 2; ++n)
#pragma unroll
                for (int kk = 0; kk < 2; ++kk)
                    acc[m + 4][n + 2] = __builtin_amdgcn_mfma_f32_16x16x32_bf16(
                        aF[m][kk], b1[n][kk], acc[m + 4][n + 2], 0, 0, 0);
        __builtin_amdgcn_s_setprio(0);
        SBAR();
        // ---- P4: stage A(g+2); MFMA (m4-7, n0-1); counted vmcnt ----------
        if (g + 2 < NK) { stA(g + 2, 0, 0); stA(g + 2, 0, 1);
                          stA(g + 2, 1, 0); stA(g + 2, 1, 1); }
        __builtin_amdgcn_s_setprio(1);
#pragma unroll
        for (int m = 0; m < 4; ++m)
#pragma unroll
            for (int n = 0; n < 2; ++n)
#pragma unroll
                for (int kk = 0; kk < 2; ++kk)
                    acc[m + 4][n] = __builtin_amdgcn_mfma_f32_16x16x32_bf16(
                        aF[m][kk], b0[n][kk], acc[m + 4][n], 0, 0, 0);
        __builtin_amdgcn_s_setprio(0);
        if (g + 2 < NK) asm volatile("s_waitcnt vmcnt(8)" ::: "memory");
        else            asm volatile("s_waitcnt vmcnt(0)" ::: "memory");
        SBAR();
    }

    // epilogue: D map col=lane&15, row=(lane>>4)*4+r; bf16 out
#pragma unroll
    for (int m = 0; m < 8; ++m) {
#pragma unroll
        for (int n = 0; n < 4; ++n) {
            const int col = n0 + wn + n * 16 + fr;
            const float bsum = bias[col];
#pragma unroll
            for (int r = 0; r < 4; ++r) {
                const int row = m0 + wm + m * 16 + fq * 4 + r;
                Zb[(size_t)row * N + col] = f2bf(acc[m][n][r] + bsum);
            }
        }
    }
}

// ---------------------------------------------------------------------------
// 128x128 / BK=32 GEMM — layer-0 (K=160) only; bf16 output.
// ---------------------------------------------------------------------------
__global__ __launch_bounds__(256) void gemm_bf16_lds(
    const short* __restrict__ A, const short* __restrict__ Bw,
    const float* __restrict__ bias,
    short* __restrict__ Zb, int M, int N, int Kb)
{
    __shared__ short As[128 * 32];
    __shared__ short Bs[128 * 32];

    const int tid = threadIdx.x;
    const int nwg = gridDim.x * gridDim.y;
    int lin = blockIdx.y * gridDim.x + blockIdx.x;
    lin = (lin & 7) * (nwg >> 3) + (lin >> 3);
    const int bx = lin % gridDim.x;
    const int by = lin / gridDim.x;
    const int m0 = by * 128;
    const int n0 = bx * 128;

    const int srow = tid >> 2;
    const int scol = (tid & 3) * 8;

    const int wid  = tid >> 6;
    const int lane = tid & 63;
    const int wm   = (wid >> 1) * 64;
    const int wn   = (wid & 1) * 64;
    const int fr   = lane & 15;
    const int fk   = (lane >> 4) * 8;

    f32x4 acc[4][4];
#pragma unroll
    for (int m = 0; m < 4; ++m)
#pragma unroll
        for (int n = 0; n < 4; ++n)
            acc[m][n] = (f32x4){0.f, 0.f, 0.f, 0.f};

    const short* Abase = A + (size_t)m0 * Kb;
    const short* Bbase = Bw + (size_t)n0 * Kb;

    for (int k0 = 0; k0 < Kb; k0 += 32) {
        gload16(Abase + (size_t)srow        * Kb + k0 + scol, &As[tid * 8]);
        gload16(Abase + (size_t)(srow + 64) * Kb + k0 + scol, &As[2048 + tid * 8]);
        gload16(Bbase + (size_t)srow        * Kb + k0 + scol, &Bs[tid * 8]);
        gload16(Bbase + (size_t)(srow + 64) * Kb + k0 + scol, &Bs[2048 + tid * 8]);
        __syncthreads();

        bf16x8 af[4], bfv[4];
#pragma unroll
        for (int m = 0; m < 4; ++m)
            af[m] = *(const bf16x8*)&As[(wm + m * 16 + fr) * 32 + fk];
#pragma unroll
        for (int n = 0; n < 4; ++n)
            bfv[n] = *(const bf16x8*)&Bs[(wn + n * 16 + fr) * 32 + fk];

#pragma unroll
        for (int m = 0; m < 4; ++m)
#pragma unroll
            for (int n = 0; n < 4; ++n)
                acc[m][n] = __builtin_amdgcn_mfma_f32_16x16x32_bf16(
                    af[m], bfv[n], acc[m][n], 0, 0, 0);
        __syncthreads();
    }

    const int orow = (lane >> 4) * 4;
#pragma unroll
    for (int m = 0; m < 4; ++m) {
#pragma unroll
        for (int n = 0; n < 4; ++n) {
            const int col = n0 + wn + n * 16 + fr;
            const float bsum = bias[col];
#pragma unroll
            for (int r = 0; r < 4; ++r) {
                const int row = m0 + wm + m * 16 + orow + r;
                Zb[(size_t)row * N + col] = f2bf(acc[m][n][r] + bsum);
            }
        }
    }
}

// ---------------------------------------------------------------------------
// IndRNN scan v3: 1 thread per (b,h) = 131072 threads (8 waves/CU, max TLP).
// bf16 z in, fp32 recurrence, bf16 h out + BN stats, 2-deep prefetch.
// store_all==0: only t=T-1 row is written.
// ---------------------------------------------------------------------------
__global__ __launch_bounds__(256) void scan_bf16_v3(
    const short* __restrict__ Zb, const float* __restrict__ u,
    short* __restrict__ Hb, float* __restrict__ sum, float* __restrict__ sumsq,
    int store_all)
{
    const int idx = blockIdx.x * blockDim.x + threadIdx.x;   // b*H + h
    const int h = idx & (H_ - 1);
    const float uu = u[h];
    float hp = 0.f, s1 = 0.f, s2 = 0.f;

    short z0 = Zb[idx];
    short z1 = Zb[(size_t)(B_ * H_) + idx];

    for (int t = 0; t < T_; ++t) {
        const short zc = z0;
        z0 = z1;
        if (t + 2 < T_) z1 = Zb[(size_t)(t + 2) * (B_ * H_) + idx];
        float hv = fmaxf(bf2f(zc) + uu * hp, 0.f);
        hp = hv;
        s1 += hv;
        s2 += hv * hv;
        if (store_all) Hb[(size_t)t * (B_ * H_) + idx] = f2bf(hv);
    }
    if (!store_all) Hb[(size_t)(T_ - 1) * (B_ * H_) + idx] = f2bf(hp);

    atomicAdd(&sum[h], s1);
    atomicAdd(&sumsq[h], s2);
}

// ---------------------------------------------------------------------------
__global__ void bn_finalize(
    const float* __restrict__ sum, const float* __restrict__ sumsq,
    const float* __restrict__ gamma, const float* __restrict__ beta,
    float* __restrict__ scale, float* __restrict__ shift)
{
    const int h = blockIdx.x * blockDim.x + threadIdx.x;
    if (h >= H_) return;
    const float inv_n = 1.f / (float)(T_ * B_);
    const float m = sum[h] * inv_n;
    const float v = sumsq[h] * inv_n - m * m;
    const float s = gamma[h] * rsqrtf(v + BN_EPS);
    scale[h] = s;
    shift[h] = beta[h] - m * s;
}

// ---------------------------------------------------------------------------
// Fused BN fold: Wb[n,k] = bf16(W[n,k]*scale[k]);
//                bias2[n] = b[n] + sum_k shift[k]*W[n,k].  One wave per row.
// ---------------------------------------------------------------------------
__global__ __launch_bounds__(256) void fold_wb(
    const float* __restrict__ Wf, const float* __restrict__ scale,
    const float* __restrict__ shift, const float* __restrict__ b,
    short* __restrict__ Wb, float* __restrict__ bias2)
{
    const int wrow = (blockIdx.x * blockDim.x + threadIdx.x) >> 6;
    const int lane = threadIdx.x & 63;
    if (wrow >= H_) return;
    const float* wr = Wf + (size_t)wrow * H_;
    short* wb = Wb + (size_t)wrow * H_;
    float acc = 0.f;
    for (int k4 = lane * 4; k4 < H_; k4 += 256) {
        float4 w  = *(const float4*)(wr + k4);
        float4 sc = *(const float4*)(scale + k4);
        float4 sh = *(const float4*)(shift + k4);
        short4 s;
        s.x = f2bf(w.x * sc.x); s.y = f2bf(w.y * sc.y);
        s.z = f2bf(w.z * sc.z); s.w = f2bf(w.w * sc.w);
        *(short4*)(wb + k4) = s;
        acc += w.x * sh.x + w.y * sh.y + w.z * sh.z + w.w * sh.w;
    }
#pragma unroll
    for (int o = 32; o > 0; o >>= 1) acc += __shfl_down(acc, o);
    if (lane == 0) bias2[wrow] = acc + b[wrow];
}

// ---------------------------------------------------------------------------
// fp32 [rows][K0REAL] -> bf16 [rows][K0PAD] zero-padded
// ---------------------------------------------------------------------------
__global__ __launch_bounds__(256) void conv_pad(
    const float* __restrict__ X, short* __restrict__ Xb, int rows)
{
    const int npr = K0PAD / 4;   // 40
    const int idx = blockIdx.x * blockDim.x + threadIdx.x;
    if (idx >= rows * npr) return;
    const int r = idx / npr;
    const int c4 = (idx - r * npr) * 4;
    short4 s = {0, 0, 0, 0};
    if (c4 < K0REAL) {
        float4 v = *(const float4*)(X + (size_t)r * K0REAL + c4);
        s.x = f2bf(v.x); s.y = f2bf(v.y); s.z = f2bf(v.z); s.w = f2bf(v.w);
    }
    *(short4*)(Xb + (size_t)r * K0PAD + c4) = s;
}

// ---------------------------------------------------------------------------
// out[b,c] = sum_h (bf2f(Hb[b,h])*scale[h]+shift[h]) * Wlast[c,h] + blast[c]
// ---------------------------------------------------------------------------
__global__ __launch_bounds__(256) void final_proj(
    const short* __restrict__ Hb, const float* __restrict__ scale,
    const float* __restrict__ shift, const float* __restrict__ Wlast,
    const float* __restrict__ blast, float* __restrict__ out)
{
    const int wave = (blockIdx.x * blockDim.x + threadIdx.x) >> 6;
    const int lane = threadIdx.x & 63;
    if (wave >= B_ * C_) return;
    const int b = wave / C_;
    const int c = wave % C_;
    float acc = 0.f;
    for (int h = lane; h < H_; h += 64) {
        float hv = bf2f(Hb[(size_t)b * H_ + h]) * scale[h] + shift[h];
        acc += hv * Wlast[(size_t)c * H_ + h];
    }
#pragma unroll
    for (int o = 32; o > 0; o >>= 1) acc += __shfl_down(acc, o);
    if (lane == 0) out[(size_t)b * C_ + c] = acc + blast[c];
}

// ---------------------------------------------------------------------------
extern "C" void kernel_launch(void* const* d_in, const int* in_sizes, int n_in,
                              void* d_out, int out_size, void* d_ws, size_t ws_size,
                              hipStream_t stream)
{
    const float* x      = (const float*)d_in[0];  // [8192,144]
    const float* W0     = (const float*)d_in[1];  // [2048,144]
    const float* Ws     = (const float*)d_in[2];  // [3,2048,2048]
    const float* bs     = (const float*)d_in[3];  // [4,2048]
    const float* us     = (const float*)d_in[4];
    const float* gammas = (const float*)d_in[5];
    const float* betas  = (const float*)d_in[6];
    const float* Wlast  = (const float*)d_in[7];  // [10,2048]
    const float* blast  = (const float*)d_in[8];
    float* out = (float*)d_out;

    char* ws = (char*)d_ws;
    short* zb      = (short*)ws;                            // 32 MB bf16 z
    short* Ab      = (short*)(ws + (size_t)32 * 1048576);   // 32 MB bf16 h
    short* Wb      = (short*)(ws + (size_t)64 * 1048576);   // 8 MB folded W
    short* X0b     = (short*)(ws + (size_t)72 * 1048576);   // 2.62 MB
    short* W0b     = (short*)(ws + (size_t)75 * 1048576);   // 0.66 MB
    float* sum     = (float*)(ws + (size_t)76 * 1048576);
    float* sumsq   = sum + H_;
    float* bnscale = sumsq + H_;
    float* bnshift = bnscale + H_;
    float* bias2   = bnshift + H_;

    const int M = T_ * B_;   // 8192

    conv_pad<<<(M * (K0PAD / 4) + 255) / 256, 256, 0, stream>>>(x, X0b, M);
    conv_pad<<<(H_ * (K0PAD / 4) + 255) / 256, 256, 0, stream>>>(W0, W0b, H_);

    // layer 0 projection (K padded to 160)
    gemm_bf16_lds<<<dim3(H_ / 128, M / 128), 256, 0, stream>>>(
        X0b, W0b, bs, zb, M, H_, K0PAD);

    const dim3 g256(M / 256, H_ / 256);   // (32, 8) = 256 blocks
    for (int l = 0; l < L_; ++l) {
        hipMemsetAsync(sum, 0, 2 * H_ * sizeof(float), stream);
        scan_bf16_v3<<<(B_ * H_) / 256, 256, 0, stream>>>(
            zb, us + l * H_, Ab, sum, sumsq, (l < L_ - 1) ? 1 : 0);
        bn_finalize<<<H_ / 256, 256, 0, stream>>>(sum, sumsq,
                                                  gammas + l * H_, betas + l * H_,
                                                  bnscale, bnshift);
        if (l < L_ - 1) {
            const float* Wl = Ws + (size_t)l * H_ * H_;
            fold_wb<<<(H_ * 64) / 256, 256, 0, stream>>>(Wl, bnscale, bnshift,
                                                         bs + (l + 1) * H_, Wb, bias2);
            gemm_bf16_8ph<<<g256, 512, 0, stream>>>(Ab, Wb, bias2, zb, M, H_, H_);
        }
    }

    final_proj<<<(B_ * C_ * 64 + 255) / 256, 256, 0, stream>>>(
        Ab + (size_t)(T_ - 1) * B_ * H_, bnscale, bnshift, Wlast, blast, out);
}

// Round 8
// 399.630 us; speedup vs baseline: 1.3601x; 1.2605x over previous
//
#include <hip/hip_runtime.h>

#define T_    128
#define B_    64
#define H_    2048
#define L_    4
#define C_    10
#define BN_EPS 1e-5f
#define K0REAL 144
#define K0PAD  160

typedef __attribute__((ext_vector_type(8))) short bf16x8;
typedef __attribute__((ext_vector_type(4))) float f32x4;

__device__ __forceinline__ short f2bf(float f) {
    union { float f; unsigned u; } v; v.f = f;
    unsigned r = (v.u + 0x7FFFu + ((v.u >> 16) & 1u)) >> 16;
    return (short)r;
}
__device__ __forceinline__ float bf2f(short s) {
    union { unsigned u; float f; } v; v.u = ((unsigned)(unsigned short)s) << 16;
    return v.f;
}
__device__ __forceinline__ void gload16(const short* g, short* l) {
    __builtin_amdgcn_global_load_lds(
        (const __attribute__((address_space(1))) void*)g,
        (__attribute__((address_space(3))) void*)l, 16, 0, 0);
}

#define SBAR() do { __builtin_amdgcn_sched_barrier(0); \
                    __builtin_amdgcn_s_barrier();      \
                    __builtin_amdgcn_sched_barrier(0); } while (0)

// ---------------------------------------------------------------------------
// 256x256 / BK=64 / 8-wave GEMM, 4 phases per K-tile, ONE barrier per phase.
// Zb[M,N](bf16) = A[M,Kb](bf16) @ Bw[N,Kb](bf16)^T + bias
// XCD-chunked block map: XCD j (lin&7) owns m-panels 4j..4j+3 x all 8
// n-panels -> per-XCD L2 footprint A 4MB + B 8MB. Counted vmcnt(8) once per
// K-tile. Grid must be (M/256, 8) = 256 blocks.  [verified rounds 5-7]
// ---------------------------------------------------------------------------
__global__ __launch_bounds__(512, 2) void gemm_bf16_8ph(
    const short* __restrict__ A, const short* __restrict__ Bw,
    const float* __restrict__ bias, short* __restrict__ Zb,
    int M, int N, int Kb)
{
    __shared__ short As[2][256 * 64];
    __shared__ short Bs[2][256 * 64];

    const int tid  = threadIdx.x;
    const int wid  = tid >> 6;
    const int lane = tid & 63;

    const int lin = blockIdx.y * gridDim.x + blockIdx.x;
    const int xcd = lin & 7;
    const int loc = lin >> 3;
    const int m0  = (xcd * 4 + (loc & 3)) * 256;
    const int n0  = (loc >> 2) * 256;

    const int wm  = (wid >> 2) * 128;
    const int wn  = (wid & 3) * 64;

    const int fr  = lane & 15;
    const int fq  = lane >> 4;
    const int fr7 = fr & 7;

    const int s_sub   = wid * 2;
    const int s_rowi  = lane >> 3;
    const int s_chunk = (lane & 7) ^ s_rowi;

    auto stA = [&](int kt, int h, int i) {
        const int r = h * 128 + (s_sub + i) * 8 + s_rowi;
        gload16(A + (size_t)(m0 + r) * Kb + kt * 64 + s_chunk * 8,
                &As[kt & 1][h * 8192 + (s_sub + i) * 512 + lane * 8]);
    };
    auto stB = [&](int kt, int h, int i) {
        const int r = h * 128 + (s_sub + i) * 8 + s_rowi;
        gload16(Bw + (size_t)(n0 + r) * Kb + kt * 64 + s_chunk * 8,
                &Bs[kt & 1][h * 8192 + (s_sub + i) * 512 + lane * 8]);
    };
    auto rdA = [&](int buf, int m, int kk) -> bf16x8 {
        const int ar = wm + m * 16 + fr;
        const int slot = (kk * 4 + fq) ^ fr7;
        return *(const bf16x8*)&As[buf][ar * 64 + slot * 8];
    };
    auto rdB = [&](int buf, int n, int kk) -> bf16x8 {
        const int br = wn + n * 16 + fr;
        const int slot = (kk * 4 + fq) ^ fr7;
        return *(const bf16x8*)&Bs[buf][br * 64 + slot * 8];
    };

    f32x4 acc[8][4];
#pragma unroll
    for (int m = 0; m < 8; ++m)
#pragma unroll
        for (int n = 0; n < 4; ++n)
            acc[m][n] = (f32x4){0.f, 0.f, 0.f, 0.f};

    const int NK = Kb >> 6;

    stA(0, 0, 0); stA(0, 0, 1); stA(0, 1, 0); stA(0, 1, 1);
    stB(0, 0, 0); stB(0, 0, 1); stB(0, 1, 0); stB(0, 1, 1);
    stA(1, 0, 0); stA(1, 0, 1); stA(1, 1, 0); stA(1, 1, 1);
    stB(1, 0, 0); stB(1, 0, 1); stB(1, 1, 0); stB(1, 1, 1);
    asm volatile("s_waitcnt vmcnt(8)" ::: "memory");
    SBAR();

    bf16x8 aF[4][2], b0[2][2], b1[2][2];

#pragma unroll 1
    for (int g = 0; g < NK; ++g) {
        const int buf = g & 1;
        // ---- P1: rd A m0-3 + B n0-1; MFMA (m0-3, n0-1) -------------------
#pragma unroll
        for (int m = 0; m < 4; ++m)
#pragma unroll
            for (int kk = 0; kk < 2; ++kk) aF[m][kk] = rdA(buf, m, kk);
#pragma unroll
        for (int n = 0; n < 2; ++n)
#pragma unroll
            for (int kk = 0; kk < 2; ++kk) b0[n][kk] = rdB(buf, n, kk);
        __builtin_amdgcn_s_setprio(1);
#pragma unroll
        for (int m = 0; m < 4; ++m)
#pragma unroll
            for (int n = 0; n < 2; ++n)
#pragma unroll
                for (int kk = 0; kk < 2; ++kk)
                    acc[m][n] = __builtin_amdgcn_mfma_f32_16x16x32_bf16(
                        aF[m][kk], b0[n][kk], acc[m][n], 0, 0, 0);
        __builtin_amdgcn_s_setprio(0);
        SBAR();
        // ---- P2: rd B n2-3; MFMA (m0-3, n2-3) ----------------------------
#pragma unroll
        for (int n = 0; n < 2; ++n)
#pragma unroll
            for (int kk = 0; kk < 2; ++kk) b1[n][kk] = rdB(buf, n + 2, kk);
        __builtin_amdgcn_s_setprio(1);
#pragma unroll
        for (int m = 0; m < 4; ++m)
#pragma unroll
            for (int n = 0; n < 2; ++n)
#pragma unroll
                for (int kk = 0; kk < 2; ++kk)
                    acc[m][n + 2] = __builtin_amdgcn_mfma_f32_16x16x32_bf16(
                        aF[m][kk], b1[n][kk], acc[m][n + 2], 0, 0, 0);
        __builtin_amdgcn_s_setprio(0);
        SBAR();
        // ---- P3: rd A m4-7; stage B(g+2); MFMA (m4-7, n2-3) --------------
#pragma unroll
        for (int m = 0; m < 4; ++m)
#pragma unroll
            for (int kk = 0; kk < 2; ++kk) aF[m][kk] = rdA(buf, m + 4, kk);
        if (g + 2 < NK) { stB(g + 2, 0, 0); stB(g + 2, 0, 1);
                          stB(g + 2, 1, 0); stB(g + 2, 1, 1); }
        __builtin_amdgcn_s_setprio(1);
#pragma unroll
        for (int m = 0; m < 4; ++m)
#pragma unroll
            for (int n = 0; n < 2; ++n)
#pragma unroll
                for (int kk = 0; kk < 2; ++kk)
                    acc[m + 4][n + 2] = __builtin_amdgcn_mfma_f32_16x16x32_bf16(
                        aF[m][kk], b1[n][kk], acc[m + 4][n + 2], 0, 0, 0);
        __builtin_amdgcn_s_setprio(0);
        SBAR();
        // ---- P4: stage A(g+2); MFMA (m4-7, n0-1); counted vmcnt ----------
        if (g + 2 < NK) { stA(g + 2, 0, 0); stA(g + 2, 0, 1);
                          stA(g + 2, 1, 0); stA(g + 2, 1, 1); }
        __builtin_amdgcn_s_setprio(1);
#pragma unroll
        for (int m = 0; m < 4; ++m)
#pragma unroll
            for (int n = 0; n < 2; ++n)
#pragma unroll
                for (int kk = 0; kk < 2; ++kk)
                    acc[m + 4][n] = __builtin_amdgcn_mfma_f32_16x16x32_bf16(
                        aF[m][kk], b0[n][kk], acc[m + 4][n], 0, 0, 0);
        __builtin_amdgcn_s_setprio(0);
        if (g + 2 < NK) asm volatile("s_waitcnt vmcnt(8)" ::: "memory");
        else            asm volatile("s_waitcnt vmcnt(0)" ::: "memory");
        SBAR();
    }

    // epilogue: D map col=lane&15, row=(lane>>4)*4+r; bf16 out
#pragma unroll
    for (int m = 0; m < 8; ++m) {
#pragma unroll
        for (int n = 0; n < 4; ++n) {
            const int col = n0 + wn + n * 16 + fr;
            const float bsum = bias[col];
#pragma unroll
            for (int r = 0; r < 4; ++r) {
                const int row = m0 + wm + m * 16 + fq * 4 + r;
                Zb[(size_t)row * N + col] = f2bf(acc[m][n][r] + bsum);
            }
        }
    }
}

// ---------------------------------------------------------------------------
// 128x128 / BK=32 GEMM — layer-0 (K=160) only; bf16 output.
// ---------------------------------------------------------------------------
__global__ __launch_bounds__(256) void gemm_bf16_lds(
    const short* __restrict__ A, const short* __restrict__ Bw,
    const float* __restrict__ bias,
    short* __restrict__ Zb, int M, int N, int Kb)
{
    __shared__ short As[128 * 32];
    __shared__ short Bs[128 * 32];

    const int tid = threadIdx.x;
    const int nwg = gridDim.x * gridDim.y;
    int lin = blockIdx.y * gridDim.x + blockIdx.x;
    lin = (lin & 7) * (nwg >> 3) + (lin >> 3);
    const int bx = lin % gridDim.x;
    const int by = lin / gridDim.x;
    const int m0 = by * 128;
    const int n0 = bx * 128;

    const int srow = tid >> 2;
    const int scol = (tid & 3) * 8;

    const int wid  = tid >> 6;
    const int lane = tid & 63;
    const int wm   = (wid >> 1) * 64;
    const int wn   = (wid & 1) * 64;
    const int fr   = lane & 15;
    const int fk   = (lane >> 4) * 8;

    f32x4 acc[4][4];
#pragma unroll
    for (int m = 0; m < 4; ++m)
#pragma unroll
        for (int n = 0; n < 4; ++n)
            acc[m][n] = (f32x4){0.f, 0.f, 0.f, 0.f};

    const short* Abase = A + (size_t)m0 * Kb;
    const short* Bbase = Bw + (size_t)n0 * Kb;

    for (int k0 = 0; k0 < Kb; k0 += 32) {
        gload16(Abase + (size_t)srow        * Kb + k0 + scol, &As[tid * 8]);
        gload16(Abase + (size_t)(srow + 64) * Kb + k0 + scol, &As[2048 + tid * 8]);
        gload16(Bbase + (size_t)srow        * Kb + k0 + scol, &Bs[tid * 8]);
        gload16(Bbase + (size_t)(srow + 64) * Kb + k0 + scol, &Bs[2048 + tid * 8]);
        __syncthreads();

        bf16x8 af[4], bfv[4];
#pragma unroll
        for (int m = 0; m < 4; ++m)
            af[m] = *(const bf16x8*)&As[(wm + m * 16 + fr) * 32 + fk];
#pragma unroll
        for (int n = 0; n < 4; ++n)
            bfv[n] = *(const bf16x8*)&Bs[(wn + n * 16 + fr) * 32 + fk];

#pragma unroll
        for (int m = 0; m < 4; ++m)
#pragma unroll
            for (int n = 0; n < 4; ++n)
                acc[m][n] = __builtin_amdgcn_mfma_f32_16x16x32_bf16(
                    af[m], bfv[n], acc[m][n], 0, 0, 0);
        __syncthreads();
    }

    const int orow = (lane >> 4) * 4;
#pragma unroll
    for (int m = 0; m < 4; ++m) {
#pragma unroll
        for (int n = 0; n < 4; ++n) {
            const int col = n0 + wn + n * 16 + fr;
            const float bsum = bias[col];
#pragma unroll
            for (int r = 0; r < 4; ++r) {
                const int row = m0 + wm + m * 16 + orow + r;
                Zb[(size_t)row * N + col] = f2bf(acc[m][n][r] + bsum);
            }
        }
    }
}

// ---------------------------------------------------------------------------
// IndRNN scan v5: 1 thread per (b,h); 8-deep chunked register prefetch.
// Issue 8 loads for chunk t+8 back-to-back, then compute chunk t -> per-step
// effective latency ~= HBM_latency/8 instead of /2.
// ---------------------------------------------------------------------------
__global__ __launch_bounds__(256) void scan_bf16_v5(
    const short* __restrict__ Zb, const float* __restrict__ u,
    short* __restrict__ Hb, float* __restrict__ sum, float* __restrict__ sumsq,
    int store_all)
{
    const int idx = blockIdx.x * blockDim.x + threadIdx.x;   // b*H + h
    const int h = idx & (H_ - 1);
    const float uu = u[h];
    const int stride = B_ * H_;
    float hp = 0.f, s1 = 0.f, s2 = 0.f;

    short zr[8];
#pragma unroll
    for (int j = 0; j < 8; ++j) zr[j] = Zb[(size_t)j * stride + idx];

#pragma unroll 1
    for (int t0 = 0; t0 < T_; t0 += 8) {
        short cur[8];
#pragma unroll
        for (int j = 0; j < 8; ++j) cur[j] = zr[j];
        if (t0 + 8 < T_) {
#pragma unroll
            for (int j = 0; j < 8; ++j)
                zr[j] = Zb[(size_t)(t0 + 8 + j) * stride + idx];
        }
#pragma unroll
        for (int j = 0; j < 8; ++j) {
            float hv = fmaxf(bf2f(cur[j]) + uu * hp, 0.f);
            hp = hv;
            s1 += hv;
            s2 += hv * hv;
            if (store_all) Hb[(size_t)(t0 + j) * stride + idx] = f2bf(hv);
        }
    }
    if (!store_all) Hb[(size_t)(T_ - 1) * stride + idx] = f2bf(hp);

    atomicAdd(&sum[h], s1);
    atomicAdd(&sumsq[h], s2);
}

// ---------------------------------------------------------------------------
__global__ void bn_finalize(
    const float* __restrict__ sum, const float* __restrict__ sumsq,
    const float* __restrict__ gamma, const float* __restrict__ beta,
    float* __restrict__ scale, float* __restrict__ shift)
{
    const int h = blockIdx.x * blockDim.x + threadIdx.x;
    if (h >= H_) return;
    const float inv_n = 1.f / (float)(T_ * B_);
    const float m = sum[h] * inv_n;
    const float v = sumsq[h] * inv_n - m * m;
    const float s = gamma[h] * rsqrtf(v + BN_EPS);
    scale[h] = s;
    shift[h] = beta[h] - m * s;
}

// ---------------------------------------------------------------------------
// Fused BN fold: Wb[n,k] = bf16(W[n,k]*scale[k]);
//                bias2[n] = b[n] + sum_k shift[k]*W[n,k].  One wave per row.
// ---------------------------------------------------------------------------
__global__ __launch_bounds__(256) void fold_wb(
    const float* __restrict__ Wf, const float* __restrict__ scale,
    const float* __restrict__ shift, const float* __restrict__ b,
    short* __restrict__ Wb, float* __restrict__ bias2)
{
    const int wrow = (blockIdx.x * blockDim.x + threadIdx.x) >> 6;
    const int lane = threadIdx.x & 63;
    if (wrow >= H_) return;
    const float* wr = Wf + (size_t)wrow * H_;
    short* wb = Wb + (size_t)wrow * H_;
    float acc = 0.f;
    for (int k4 = lane * 4; k4 < H_; k4 += 256) {
        float4 w  = *(const float4*)(wr + k4);
        float4 sc = *(const float4*)(scale + k4);
        float4 sh = *(const float4*)(shift + k4);
        short4 s;
        s.x = f2bf(w.x * sc.x); s.y = f2bf(w.y * sc.y);
        s.z = f2bf(w.z * sc.z); s.w = f2bf(w.w * sc.w);
        *(short4*)(wb + k4) = s;
        acc += w.x * sh.x + w.y * sh.y + w.z * sh.z + w.w * sh.w;
    }
#pragma unroll
    for (int o = 32; o > 0; o >>= 1) acc += __shfl_down(acc, o);
    if (lane == 0) bias2[wrow] = acc + b[wrow];
}

// ---------------------------------------------------------------------------
// Merged conversion: rows 0..8191 -> x, rows 8192..10239 -> W0.
// fp32 [.][144] -> bf16 [.][160] zero-padded.
// ---------------------------------------------------------------------------
__global__ __launch_bounds__(256) void conv_pad2(
    const float* __restrict__ X, const float* __restrict__ W0,
    short* __restrict__ Xb, short* __restrict__ W0b)
{
    const int npr = K0PAD / 4;   // 40
    const int total = (T_ * B_ + H_) * npr;
    const int idx = blockIdx.x * blockDim.x + threadIdx.x;
    if (idx >= total) return;
    const int r = idx / npr;
    const int c4 = (idx - r * npr) * 4;
    const float* src;
    short* dst;
    if (r < T_ * B_) { src = X + (size_t)r * K0REAL;            dst = Xb + (size_t)r * K0PAD; }
    else             { src = W0 + (size_t)(r - T_ * B_) * K0REAL; dst = W0b + (size_t)(r - T_ * B_) * K0PAD; }
    short4 s = {0, 0, 0, 0};
    if (c4 < K0REAL) {
        float4 v = *(const float4*)(src + c4);
        s.x = f2bf(v.x); s.y = f2bf(v.y); s.z = f2bf(v.z); s.w = f2bf(v.w);
    }
    *(short4*)(dst + c4) = s;
}

// ---------------------------------------------------------------------------
// out[b,c] = sum_h (bf2f(Hb[b,h])*scale[h]+shift[h]) * Wlast[c,h] + blast[c]
// ---------------------------------------------------------------------------
__global__ __launch_bounds__(256) void final_proj(
    const short* __restrict__ Hb, const float* __restrict__ scale,
    const float* __restrict__ shift, const float* __restrict__ Wlast,
    const float* __restrict__ blast, float* __restrict__ out)
{
    const int wave = (blockIdx.x * blockDim.x + threadIdx.x) >> 6;
    const int lane = threadIdx.x & 63;
    if (wave >= B_ * C_) return;
    const int b = wave / C_;
    const int c = wave % C_;
    float acc = 0.f;
    for (int h = lane; h < H_; h += 64) {
        float hv = bf2f(Hb[(size_t)b * H_ + h]) * scale[h] + shift[h];
        acc += hv * Wlast[(size_t)c * H_ + h];
    }
#pragma unroll
    for (int o = 32; o > 0; o >>= 1) acc += __shfl_down(acc, o);
    if (lane == 0) out[(size_t)b * C_ + c] = acc + blast[c];
}

// ---------------------------------------------------------------------------
extern "C" void kernel_launch(void* const* d_in, const int* in_sizes, int n_in,
                              void* d_out, int out_size, void* d_ws, size_t ws_size,
                              hipStream_t stream)
{
    const float* x      = (const float*)d_in[0];  // [8192,144]
    const float* W0     = (const float*)d_in[1];  // [2048,144]
    const float* Ws     = (const float*)d_in[2];  // [3,2048,2048]
    const float* bs     = (const float*)d_in[3];  // [4,2048]
    const float* us     = (const float*)d_in[4];
    const float* gammas = (const float*)d_in[5];
    const float* betas  = (const float*)d_in[6];
    const float* Wlast  = (const float*)d_in[7];  // [10,2048]
    const float* blast  = (const float*)d_in[8];
    float* out = (float*)d_out;

    char* ws = (char*)d_ws;
    short* zb      = (short*)ws;                            // 32 MB bf16 z
    short* Ab      = (short*)(ws + (size_t)32 * 1048576);   // 32 MB bf16 h
    short* Wb      = (short*)(ws + (size_t)64 * 1048576);   // 8 MB folded W
    short* X0b     = (short*)(ws + (size_t)72 * 1048576);   // 2.62 MB
    short* W0b     = (short*)(ws + (size_t)75 * 1048576);   // 0.66 MB
    float* sums    = (float*)(ws + (size_t)76 * 1048576);   // [4][H] sums
    float* sumsqs  = sums + 4 * H_;                         // [4][H] sumsq
    float* bnscale = sumsqs + 4 * H_;
    float* bnshift = bnscale + H_;
    float* bias2   = bnshift + H_;

    const int M = T_ * B_;   // 8192

    // one memset for all layers' BN stats (64 KB)
    hipMemsetAsync(sums, 0, 8 * H_ * sizeof(float), stream);

    conv_pad2<<<((M + H_) * (K0PAD / 4) + 255) / 256, 256, 0, stream>>>(
        x, W0, X0b, W0b);

    // layer 0 projection (K padded to 160)
    gemm_bf16_lds<<<dim3(H_ / 128, M / 128), 256, 0, stream>>>(
        X0b, W0b, bs, zb, M, H_, K0PAD);

    const dim3 g256(M / 256, H_ / 256);   // (32, 8) = 256 blocks
    for (int l = 0; l < L_; ++l) {
        scan_bf16_v5<<<(B_ * H_) / 256, 256, 0, stream>>>(
            zb, us + l * H_, Ab, sums + l * H_, sumsqs + l * H_,
            (l < L_ - 1) ? 1 : 0);
        bn_finalize<<<H_ / 256, 256, 0, stream>>>(sums + l * H_, sumsqs + l * H_,
                                                  gammas + l * H_, betas + l * H_,
                                                  bnscale, bnshift);
        if (l < L_ - 1) {
            const float* Wl = Ws + (size_t)l * H_ * H_;
            fold_wb<<<(H_ * 64) / 256, 256, 0, stream>>>(Wl, bnscale, bnshift,
                                                         bs + (l + 1) * H_, Wb, bias2);
            gemm_bf16_8ph<<<g256, 512, 0, stream>>>(Ab, Wb, bias2, zb, M, H_, H_);
        }
    }

    final_proj<<<(B_ * C_ * 64 + 255) / 256, 256, 0, stream>>>(
        Ab + (size_t)(T_ - 1) * B_ * H_, bnscale, bnshift, Wlast, blast, out);
}